// Round 2
// baseline (6957.702 us; speedup 1.0000x reference)
//
#include <hip/hip_runtime.h>

// GRUAdder: B=1048576 independent sequences, T=4, I=2, H=16, fp32.
// One thread per batch element, fully unrolled recurrence in registers.
// All weights staged in LDS (broadcast ds_read_b128, conflict-free).
// hidden_table written as two 128B-line-complete bursts per thread (t0+t1,
// t2+t3) to avoid partial-line RMW in L2/HBM.

constexpr long long Bn = 1048576;

__device__ __forceinline__ float fast_rcp(float x) { return __builtin_amdgcn_rcpf(x); }
__device__ __forceinline__ float sigm_f(float x) {
    return fast_rcp(1.0f + __expf(-x));
}
__device__ __forceinline__ float tanh_f(float x) {
    return 1.0f - 2.0f * fast_rcp(1.0f + __expf(2.0f * x));
}

struct SWeights {
    float4  whh[48 * 4];   // [48][16] as float4 quads
    float2  wih[48];       // [48][2]
    float   brz[32];       // b_ih + b_hh folded, r and z gates
    float   bin[16];       // b_ih, n gate
    float   bhn[16];       // b_hh, n gate
    float4  wsum[4];       // [16]
    float4  wcar[4];       // [16]
    float   bsum, bcar;
};

// One GRU step: hp (prev hidden) -> hn. x0,x1 = inputs at this t.
__device__ __forceinline__ void gru_step(float x0, float x1,
                                         const float* hp, float* hn,
                                         const SWeights* sw) {
#pragma unroll
    for (int j = 0; j < 16; ++j) {
        const float2 wr = sw->wih[j];
        const float2 wz = sw->wih[16 + j];
        const float2 wn = sw->wih[32 + j];
        float gr = fmaf(x1, wr.y, fmaf(x0, wr.x, sw->brz[j]));
        float gz = fmaf(x1, wz.y, fmaf(x0, wz.x, sw->brz[16 + j]));
        float gn = fmaf(x1, wn.y, fmaf(x0, wn.x, sw->bin[j]));
        float hg = sw->bhn[j];
#pragma unroll
        for (int q = 0; q < 4; ++q) {
            const float4 wr4 = sw->whh[j * 4 + q];
            const float4 wz4 = sw->whh[(16 + j) * 4 + q];
            const float4 wn4 = sw->whh[(32 + j) * 4 + q];
            const float h0 = hp[q * 4 + 0], h1 = hp[q * 4 + 1];
            const float h2 = hp[q * 4 + 2], h3 = hp[q * 4 + 3];
            gr = fmaf(h3, wr4.w, fmaf(h2, wr4.z, fmaf(h1, wr4.y, fmaf(h0, wr4.x, gr))));
            gz = fmaf(h3, wz4.w, fmaf(h2, wz4.z, fmaf(h1, wz4.y, fmaf(h0, wz4.x, gz))));
            hg = fmaf(h3, wn4.w, fmaf(h2, wn4.z, fmaf(h1, wn4.y, fmaf(h0, wn4.x, hg))));
        }
        const float r = sigm_f(gr);
        const float z = sigm_f(gz);
        const float n = tanh_f(fmaf(r, hg, gn));
        hn[j] = fmaf(z, hp[j] - n, n);  // (1-z)*n + z*hp
    }
}

__device__ __forceinline__ float dot16(const float* h, const float4* w4, float init) {
    float s = init;
#pragma unroll
    for (int q = 0; q < 4; ++q) {
        const float4 w = w4[q];
        s = fmaf(h[q * 4 + 3], w.w, fmaf(h[q * 4 + 2], w.z,
            fmaf(h[q * 4 + 1], w.y, fmaf(h[q * 4 + 0], w.x, s))));
    }
    return s;
}

__device__ __forceinline__ void store16(float4* dst, const float* h) {
    dst[0] = make_float4(h[0], h[1], h[2], h[3]);
    dst[1] = make_float4(h[4], h[5], h[6], h[7]);
    dst[2] = make_float4(h[8], h[9], h[10], h[11]);
    dst[3] = make_float4(h[12], h[13], h[14], h[15]);
}

__global__ __launch_bounds__(256) void gru_adder_kernel(
    const float* __restrict__ x_bits,   // [B, 4, 2]
    const float* __restrict__ w_ih,     // [48, 2]
    const float* __restrict__ w_hh,     // [48, 16]
    const float* __restrict__ b_ih,     // [48]
    const float* __restrict__ b_hh,     // [48]
    const float* __restrict__ w_sum,    // [16]
    const float* __restrict__ b_sum,    // [1]
    const float* __restrict__ w_carry,  // [16]
    const float* __restrict__ b_carry,  // [1]
    float* __restrict__ out)
{
    __shared__ SWeights sw;

    const int tid = threadIdx.x;
    {
        float* whhf = (float*)sw.whh;
        for (int i = tid; i < 768; i += 256) whhf[i] = w_hh[i];
        if (tid < 96) ((float*)sw.wih)[tid] = w_ih[tid];
        if (tid < 32) sw.brz[tid] = b_ih[tid] + b_hh[tid];
        else if (tid < 64) {
            sw.bin[tid - 32 - 16 * (tid >= 48)] = 0.0f;  // placeholder overwritten below
        }
        if (tid >= 32 && tid < 48) { sw.bin[tid - 32] = b_ih[tid]; sw.bhn[tid - 32] = b_hh[tid]; }
        if (tid >= 64 && tid < 80) {
            ((float*)sw.wsum)[tid - 64] = w_sum[tid - 64];
            ((float*)sw.wcar)[tid - 64] = w_carry[tid - 64];
        }
        if (tid == 96) { sw.bsum = b_sum[0]; sw.bcar = b_carry[0]; }
    }
    __syncthreads();

    const long long b = (long long)blockIdx.x * blockDim.x + tid;

    const float4* xp = (const float4*)(x_bits + b * 8);
    const float4 xv0 = xp[0];
    const float4 xv1 = xp[1];

    float ha[16], hb[16], sums[4];

    // ---- t = 0 (h == 0): gate = x@w_ih + b_ih + b_hh-contrib ----
#pragma unroll
    for (int j = 0; j < 16; ++j) {
        const float2 wr = sw.wih[j];
        const float2 wz = sw.wih[16 + j];
        const float2 wn = sw.wih[32 + j];
        const float gr = fmaf(xv0.y, wr.y, fmaf(xv0.x, wr.x, sw.brz[j]));
        const float gz = fmaf(xv0.y, wz.y, fmaf(xv0.x, wz.x, sw.brz[16 + j]));
        const float gn = fmaf(xv0.y, wn.y, fmaf(xv0.x, wn.x, sw.bin[j]));
        const float r = sigm_f(gr);
        const float z = sigm_f(gz);
        const float n = tanh_f(fmaf(r, sw.bhn[j], gn));
        ha[j] = n - z * n;
    }
    sums[0] = dot16(ha, sw.wsum, sw.bsum);

    // ---- t = 1 ----
    gru_step(xv0.z, xv0.w, ha, hb, &sw);
    sums[1] = dot16(hb, sw.wsum, sw.bsum);

    // store hidden_table t0,t1 as one 128B-contiguous burst
    {
        float4* hp4 = (float4*)(out + b * 64);
        store16(hp4, ha);
        store16(hp4 + 4, hb);
    }

    // ---- t = 2 ----
    gru_step(xv1.x, xv1.y, hb, ha, &sw);
    sums[2] = dot16(ha, sw.wsum, sw.bsum);

    // ---- t = 3 ----
    gru_step(xv1.z, xv1.w, ha, hb, &sw);
    sums[3] = dot16(hb, sw.wsum, sw.bsum);

    // store hidden_table t2,t3
    {
        float4* hp4 = (float4*)(out + b * 64 + 32);
        store16(hp4, ha);
        store16(hp4 + 4, hb);
    }

    const float c = dot16(hb, sw.wcar, sw.bcar);

    // sum_logits [B,4] @ 64*B
    ((float4*)(out + 64ll * Bn))[b] = make_float4(sums[0], sums[1], sums[2], sums[3]);

    // carry_logit [B,1] @ 68*B
    out[68ll * Bn + b] = c;

    // output_logits [B,5] @ 69*B
    float* ol = out + 69ll * Bn + b * 5;
    ol[0] = sums[0];
    ol[1] = sums[1];
    ol[2] = sums[2];
    ol[3] = sums[3];
    ol[4] = c;
}

extern "C" void kernel_launch(void* const* d_in, const int* in_sizes, int n_in,
                              void* d_out, int out_size, void* d_ws, size_t ws_size,
                              hipStream_t stream) {
    const float* x_bits  = (const float*)d_in[0];
    const float* w_ih    = (const float*)d_in[1];
    const float* w_hh    = (const float*)d_in[2];
    const float* b_ih    = (const float*)d_in[3];
    const float* b_hh    = (const float*)d_in[4];
    const float* w_sum   = (const float*)d_in[5];
    const float* b_sum   = (const float*)d_in[6];
    const float* w_carry = (const float*)d_in[7];
    const float* b_carry = (const float*)d_in[8];
    float* out = (float*)d_out;

    const int block = 256;
    const int grid = (int)((Bn + block - 1) / block);  // 4096
    gru_adder_kernel<<<grid, block, 0, stream>>>(
        x_bits, w_ih, w_hh, b_ih, b_hh, w_sum, b_sum, w_carry, b_carry, out);
}